// Round 3
// baseline (171.488 us; speedup 1.0000x reference)
//
#include <hip/hip_runtime.h>

// B = 4_194_304 rows. Per row: inputs[3] f32, targets[3] i32, cycle_state i32.
// out = mean_B( sw * (0.5*(d0+d1) + d2) ) + sum_B( range_penalty )
//
// R3: one quad (4 rows) per thread, no grid-stride loop -> all 7x16B loads
// issue back-to-back (max MLP), 4096 blocks x 256 threads == nquads threads.
// Single kernel; per-block double partial -> one fp32 atomicAdd into d_out[0].

#define NTHREADS 256

// 2^-22 : exact power-of-two scaling for the mean over B
#define INV_B 2.384185791015625e-07f

typedef float f32x4 __attribute__((ext_vector_type(4)));
typedef int   i32x4 __attribute__((ext_vector_type(4)));

__global__ __launch_bounds__(NTHREADS) void wmse_main(
    const f32x4* __restrict__ in4,      // [B*3/4] view of inputs
    const i32x4* __restrict__ tg4,      // [B*3/4] view of targets
    const i32x4* __restrict__ st4,      // [B/4]   view of states
    const float* __restrict__ weights,  // [7]
    float*       __restrict__ out)      // [1], pre-zeroed
{
    __shared__ float w[8];
    if (threadIdx.x < 7) w[threadIdx.x] = weights[threadIdx.x];
    __syncthreads();

    const int q = blockIdx.x * NTHREADS + threadIdx.x;   // quad index, exact fit

    // 4 rows = 48 contiguous bytes of inputs/targets + 16 B of states.
    // All 7 loads independent -> issued back-to-back, deep MLP.
    f32x4 a  = __builtin_nontemporal_load(in4 + 3 * q + 0);
    f32x4 b  = __builtin_nontemporal_load(in4 + 3 * q + 1);
    f32x4 c  = __builtin_nontemporal_load(in4 + 3 * q + 2);
    i32x4 ta = __builtin_nontemporal_load(tg4 + 3 * q + 0);
    i32x4 tb = __builtin_nontemporal_load(tg4 + 3 * q + 1);
    i32x4 tc = __builtin_nontemporal_load(tg4 + 3 * q + 2);
    i32x4 s  = __builtin_nontemporal_load(st4 + q);

    float fin[12] = {a[0], a[1], a[2], a[3], b[0], b[1], b[2], b[3],
                     c[0], c[1], c[2], c[3]};
    int   tgt[12] = {ta[0], ta[1], ta[2], ta[3], tb[0], tb[1], tb[2], tb[3],
                     tc[0], tc[1], tc[2], tc[3]};
    int    st[4]  = {s[0], s[1], s[2], s[3]};

    double acc = 0.0;
    #pragma unroll
    for (int r = 0; r < 4; ++r) {
        const float i0 = fin[3 * r + 0];
        const float i1 = fin[3 * r + 1];
        const float i2 = fin[3 * r + 2];
        const int  t2i = tgt[3 * r + 2];
        const float t0 = (float)tgt[3 * r + 0];   // exact: < 2^24
        const float t1 = (float)tgt[3 * r + 1];
        const float t2 = (float)t2i;

        const float sw = w[t2i / 100 - 1];        // t2i in {100..700}

        const float d0 = (i0 - t0) * (i0 - t0);
        const float d1 = (i1 - t1) * (i1 - t1);
        const float d2 = (i2 - t2) * (i2 - t2);
        const float mse = sw * (0.5f * (d0 + d1) + d2);

        // range tables (idx = state-1, in [0,21))
        const int idx = st[r] - 1;
        const float lo02 = (idx == 3) ? 6400.0f
                         : ((idx >= 4 && idx <= 7) ? 6000.0f : 11500.0f);
        const float hi02 = 12000.0f;
        const float lo03 = 2200.0f;
        const float hi03 = (idx == 7) ? 13000.0f : 2500.0f;

        float p = 0.0f;
        {
            const float dl = t0 - lo02, dh = t0 - hi02;
            p += (t0 < lo02) ? dl * dl : 0.0f;
            p += (t0 > hi02) ? dh * dh : 0.0f;
        }
        {
            const float dl = t1 - lo03, dh = t1 - hi03;
            p += (t1 < lo03) ? dl * dl : 0.0f;
            p += (t1 > hi03) ? dh * dh : 0.0f;
        }

        acc += (double)(mse * INV_B) + (double)p;
    }

    // wave-64 shuffle reduce
    #pragma unroll
    for (int o = 32; o > 0; o >>= 1) acc += __shfl_down(acc, o, 64);
    __shared__ double sacc[NTHREADS / 64];
    const int lane = threadIdx.x & 63;
    const int wave = threadIdx.x >> 6;
    if (lane == 0) sacc[wave] = acc;
    __syncthreads();
    if (threadIdx.x == 0) {
        double ssum = 0.0;
        #pragma unroll
        for (int wv = 0; wv < NTHREADS / 64; ++wv) ssum += sacc[wv];
        atomicAdd(out, (float)ssum);   // device-scope by default on global
    }
}

extern "C" void kernel_launch(void* const* d_in, const int* in_sizes, int n_in,
                              void* d_out, int out_size, void* d_ws, size_t ws_size,
                              hipStream_t stream) {
    const float* inputs  = (const float*)d_in[0];   // [B,3] f32
    const int*   targets = (const int*)  d_in[1];   // [B,3] i32
    const int*   states  = (const int*)  d_in[2];   // [B]   i32
    const float* weights = (const float*)d_in[3];   // [7]   f32

    const int B = in_sizes[2];        // cycle_states is [B]
    const int nquads = B / 4;         // B = 2^22 -> 1,048,576 quads
    const int nblocks = nquads / NTHREADS;  // 4096, exact

    float* out = (float*)d_out;

    // zero the fp32 accumulator (harness poisons d_out to 0xAA before each call)
    hipMemsetAsync(out, 0, sizeof(float), stream);

    wmse_main<<<nblocks, NTHREADS, 0, stream>>>(
        (const f32x4*)inputs, (const i32x4*)targets, (const i32x4*)states,
        weights, out);
}

// Round 4
// 141.493 us; speedup vs baseline: 1.2120x; 1.2120x over previous
//
#include <hip/hip_runtime.h>

// B = 4_194_304 rows. Per row: inputs[3] f32, targets[3] i32, cycle_state i32.
// out = mean_B( sw * (0.5*(d0+d1) + d2) ) + sum_B( range_penalty )
//
// R4: 4 quads per thread, compile-time unrolled, block-strided (coalesced).
// All 28x16B loads per thread are independent -> deep MLP before first wait.
// Plain (cached) loads: inputs are L3-resident from the harness restore.
// All-float accumulation (error << 4.5e12 threshold); 1024 block atomics.

#define NTHREADS 256
#define QPT 4                      // quads per thread (16 rows)

// 2^-22 : exact power-of-two scaling for the mean over B
#define INV_B 2.384185791015625e-07f

typedef float f32x4 __attribute__((ext_vector_type(4)));
typedef int   i32x4 __attribute__((ext_vector_type(4)));

__global__ __launch_bounds__(NTHREADS) void wmse_main(
    const f32x4* __restrict__ in4,      // [B*3/4] view of inputs
    const i32x4* __restrict__ tg4,      // [B*3/4] view of targets
    const i32x4* __restrict__ st4,      // [B/4]   view of states
    const float* __restrict__ weights,  // [7]
    float*       __restrict__ out)      // [1], pre-zeroed
{
    __shared__ float w[8];
    if (threadIdx.x < 7) w[threadIdx.x] = weights[threadIdx.x];
    __syncthreads();

    const int base = blockIdx.x * (NTHREADS * QPT) + threadIdx.x;

    // Issue ALL loads first — 28 independent global_load_dwordx4, coalesced
    // (within each j, lane i reads consecutive 16B chunks).
    f32x4 A[QPT][3];
    i32x4 T[QPT][3];
    i32x4 S[QPT];
    #pragma unroll
    for (int j = 0; j < QPT; ++j) {
        const int q = base + j * NTHREADS;
        A[j][0] = in4[3 * q + 0];
        A[j][1] = in4[3 * q + 1];
        A[j][2] = in4[3 * q + 2];
        T[j][0] = tg4[3 * q + 0];
        T[j][1] = tg4[3 * q + 1];
        T[j][2] = tg4[3 * q + 2];
        S[j]    = st4[q];
    }

    float acc = 0.0f;
    #pragma unroll
    for (int j = 0; j < QPT; ++j) {
        float fin[12] = {A[j][0][0], A[j][0][1], A[j][0][2], A[j][0][3],
                         A[j][1][0], A[j][1][1], A[j][1][2], A[j][1][3],
                         A[j][2][0], A[j][2][1], A[j][2][2], A[j][2][3]};
        int   tgt[12] = {T[j][0][0], T[j][0][1], T[j][0][2], T[j][0][3],
                         T[j][1][0], T[j][1][1], T[j][1][2], T[j][1][3],
                         T[j][2][0], T[j][2][1], T[j][2][2], T[j][2][3]};
        int    st[4]  = {S[j][0], S[j][1], S[j][2], S[j][3]};

        #pragma unroll
        for (int r = 0; r < 4; ++r) {
            const float i0 = fin[3 * r + 0];
            const float i1 = fin[3 * r + 1];
            const float i2 = fin[3 * r + 2];
            const int  t2i = tgt[3 * r + 2];
            const float t0 = (float)tgt[3 * r + 0];   // exact: < 2^24
            const float t1 = (float)tgt[3 * r + 1];
            const float t2 = (float)t2i;

            const float sw = w[t2i / 100 - 1];        // t2i in {100..700}

            const float d0 = (i0 - t0) * (i0 - t0);
            const float d1 = (i1 - t1) * (i1 - t1);
            const float d2 = (i2 - t2) * (i2 - t2);
            const float mse = sw * (0.5f * (d0 + d1) + d2);

            // range tables (idx = state-1, in [0,21))
            const int idx = st[r] - 1;
            const float lo02 = (idx == 3) ? 6400.0f
                             : ((idx >= 4 && idx <= 7) ? 6000.0f : 11500.0f);
            const float hi02 = 12000.0f;
            const float lo03 = 2200.0f;
            const float hi03 = (idx == 7) ? 13000.0f : 2500.0f;

            float p = 0.0f;
            {
                const float dl = t0 - lo02, dh = t0 - hi02;
                p += (t0 < lo02) ? dl * dl : 0.0f;
                p += (t0 > hi02) ? dh * dh : 0.0f;
            }
            {
                const float dl = t1 - lo03, dh = t1 - hi03;
                p += (t1 < lo03) ? dl * dl : 0.0f;
                p += (t1 > hi03) ? dh * dh : 0.0f;
            }

            acc += mse * INV_B + p;
        }
    }

    // wave-64 shuffle reduce (float)
    #pragma unroll
    for (int o = 32; o > 0; o >>= 1) acc += __shfl_down(acc, o, 64);
    __shared__ float sacc[NTHREADS / 64];
    const int lane = threadIdx.x & 63;
    const int wave = threadIdx.x >> 6;
    if (lane == 0) sacc[wave] = acc;
    __syncthreads();
    if (threadIdx.x == 0) {
        float ssum = 0.0f;
        #pragma unroll
        for (int wv = 0; wv < NTHREADS / 64; ++wv) ssum += sacc[wv];
        atomicAdd(out, ssum);   // device-scope by default on global
    }
}

extern "C" void kernel_launch(void* const* d_in, const int* in_sizes, int n_in,
                              void* d_out, int out_size, void* d_ws, size_t ws_size,
                              hipStream_t stream) {
    const float* inputs  = (const float*)d_in[0];   // [B,3] f32
    const int*   targets = (const int*)  d_in[1];   // [B,3] i32
    const int*   states  = (const int*)  d_in[2];   // [B]   i32
    const float* weights = (const float*)d_in[3];   // [7]   f32

    const int B = in_sizes[2];            // cycle_states is [B]
    const int nquads = B / 4;             // 2^20 quads
    const int nblocks = nquads / (NTHREADS * QPT);  // 1024, exact

    float* out = (float*)d_out;

    // zero the fp32 accumulator (harness poisons d_out to 0xAA before each call)
    hipMemsetAsync(out, 0, sizeof(float), stream);

    wmse_main<<<nblocks, NTHREADS, 0, stream>>>(
        (const f32x4*)inputs, (const i32x4*)targets, (const i32x4*)states,
        weights, out);
}